// Round 4
// baseline (233.373 us; speedup 1.0000x reference)
//
#include <hip/hip_runtime.h>
#include <math.h>

// Density-Aware Chamfer Loss, B=4, N=8192, fp32 3D points — single fused kernel.
//
// NN argmin in expanded form k_j = |t_j|^2 - 2 q.t_j (same argmin as true dist).
// Target slices staged in LDS with a 2-deep register software pipeline so the
// ds_read latency (~120 cyc) is covered by ~100 cyc of VALU per iteration.
// Per-slice partial argmins merged via packed u64 atomicMin:
//   key = (monotone_f32(k) << 32) | global_idx   -> lowest-index tie-break,
// matching jnp.argmin.
//
// Count histogram + per-direction loss + final d_out copy are fused in via
// threadfence-reduction arrival counters (agent scope, G16-safe):
//   L1: last of NSLICE slice-blocks per (bz,qchunk)  -> count that qchunk
//   L2: last of QCH counting blocks per bz           -> loss for that bz
//   L3: last of 2B loss blocks                       -> copy wloss -> d_out
//
// ws: [keys 2BN u64 | cnt 2BN int | arr1 2B*QCH int | arr2 2B int | arr3 1 int | wloss B float]
// Dispatches: memset(keys=0xFF), memset(zeros), fused kernel.

#define NPTS   8192
#define QPT    4                    // queries per thread
#define BLK    256
#define TSL    512                  // targets per slice (8KB LDS as float4)
#define NSLICE (NPTS / TSL)         // 16
#define QCH    (NPTS / (QPT * BLK)) // 8

__global__ __launch_bounds__(BLK, 4) void dacl_fused(
    const float* __restrict__ gts, const float* __restrict__ preds,
    unsigned long long* __restrict__ keys, int* __restrict__ cnt,
    int* __restrict__ arr1, int* __restrict__ arr2, int* __restrict__ arr3,
    float* __restrict__ wloss, float* __restrict__ out, int B, int N)
{
    const int bz  = blockIdx.z;      // dir*B + b
    const int dir = bz / B;
    const int b   = bz - dir * B;

    const float* __restrict__ q = (dir == 0 ? gts : preds) + (size_t)b * N * 3;
    const float* __restrict__ t = (dir == 0 ? preds : gts) + (size_t)b * N * 3;

    __shared__ float4 tile[TSL + 2];   // +2 pad for the prefetch pipeline
    __shared__ float  wsum[BLK / 64];
    __shared__ int    lastflag;

    const int tbase = blockIdx.y * TSL;
    for (int k = threadIdx.x; k < TSL; k += BLK) {
        const int j = tbase + k;
        const float tx = t[3 * j], ty = t[3 * j + 1], tz = t[3 * j + 2];
        tile[k] = make_float4(tx, ty, tz, tx * tx + ty * ty + tz * tz);
    }
    if (threadIdx.x < 2) tile[TSL + threadIdx.x] = make_float4(0.f, 0.f, 0.f, 0.f);
    __syncthreads();

    float m2x[QPT], m2y[QPT], m2z[QPT], best[QPT];
    int   bi[QPT];
    const int qbase = blockIdx.x * (QPT * BLK);
    #pragma unroll
    for (int u = 0; u < QPT; ++u) {
        const int i = qbase + u * BLK + threadIdx.x;   // coalesced across lanes
        m2x[u]  = -2.0f * q[3 * i];
        m2y[u]  = -2.0f * q[3 * i + 1];
        m2z[u]  = -2.0f * q[3 * i + 2];
        best[u] = 3.402823466e38f;
        bi[u]   = 0;
    }

    // hot loop, 2-deep register pipeline: compute tile[j] while ds_read of
    // tile[j+2] is in flight (~100 cyc VALU cover vs ~120 cyc LDS latency)
    float4 tv0 = tile[0], tv1 = tile[1];
    #pragma unroll 2
    for (int j = 0; j < TSL; ++j) {
        const float4 cur = tv0;
        tv0 = tv1;
        tv1 = tile[j + 2];                  // pad entries: prefetched, never used
        #pragma unroll
        for (int u = 0; u < QPT; ++u) {
            const float k = fmaf(m2x[u], cur.x,
                            fmaf(m2y[u], cur.y,
                            fmaf(m2z[u], cur.z, cur.w)));
            if (k < best[u]) { best[u] = k; bi[u] = j; }  // strict <: first-min wins
        }
    }

    const size_t obase = (size_t)bz * N;
    #pragma unroll
    for (int u = 0; u < QPT; ++u) {
        const int i = qbase + u * BLK + threadIdx.x;
        unsigned int ub = __float_as_uint(best[u]);
        ub = ((int)ub < 0) ? ~ub : (ub | 0x80000000u);   // monotone f32->u32 (k can be <0)
        const unsigned long long key =
            ((unsigned long long)ub << 32) | (unsigned int)(tbase + bi[u]);
        atomicMin(&keys[obase + i], key);                // equal dist -> smallest idx wins
    }

    // ---- L1 arrival: last of NSLICE slice-blocks for (bz, qchunk) counts it
    __threadfence();
    __syncthreads();
    if (threadIdx.x == 0) {
        const int prev = __hip_atomic_fetch_add(&arr1[bz * QCH + blockIdx.x], 1,
                             __ATOMIC_ACQ_REL, __HIP_MEMORY_SCOPE_AGENT);
        lastflag = (prev == NSLICE - 1);
    }
    __syncthreads();
    if (!lastflag) return;                               // block-uniform

    #pragma unroll
    for (int u = 0; u < QPT; ++u) {
        const int i = qbase + u * BLK + threadIdx.x;
        const unsigned long long key = __hip_atomic_load(&keys[obase + i],
                 __ATOMIC_RELAXED, __HIP_MEMORY_SCOPE_AGENT);
        const int idx = (int)(key & 0xFFFFFFFFull);
        atomicAdd(&cnt[obase + idx], 1);
    }

    // ---- L2 arrival: last of QCH counting blocks for bz computes its loss
    __threadfence();
    __syncthreads();
    if (threadIdx.x == 0) {
        const int prev = __hip_atomic_fetch_add(&arr2[bz], 1,
                             __ATOMIC_ACQ_REL, __HIP_MEMORY_SCOPE_AGENT);
        lastflag = (prev == QCH - 1);
    }
    __syncthreads();
    if (!lastflag) return;

    float s = 0.0f;
    for (int i = threadIdx.x; i < N; i += BLK) {
        const unsigned long long key = __hip_atomic_load(&keys[obase + i],
                 __ATOMIC_RELAXED, __HIP_MEMORY_SCOPE_AGENT);
        const int idx = (int)(key & 0xFFFFFFFFull);
        // recompute true NN distance exactly like the reference's gather form
        const float dx = q[3 * i]     - t[3 * idx];
        const float dy = q[3 * i + 1] - t[3 * idx + 1];
        const float dz = q[3 * i + 2] - t[3 * idx + 2];
        const float d  = dx * dx + dy * dy + dz * dz;
        const int   c  = __hip_atomic_load(&cnt[obase + idx],
                 __ATOMIC_RELAXED, __HIP_MEMORY_SCOPE_AGENT);
        s += 1.0f - expf(-d) / ((float)c + 1e-6f);       // count^1, frac terms = 1
    }
    for (int off = 32; off > 0; off >>= 1) s += __shfl_down(s, off, 64);
    if ((threadIdx.x & 63) == 0) wsum[threadIdx.x >> 6] = s;
    __syncthreads();

    if (threadIdx.x == 0) {
        float tot = 0.f;
        #pragma unroll
        for (int w = 0; w < BLK / 64; ++w) tot += wsum[w];
        atomicAdd(&wloss[b], tot / (2.0f * (float)N));   // (mean1+mean2)/2

        // ---- L3 arrival: last of 2B loss blocks publishes d_out
        __threadfence();
        const int prev = __hip_atomic_fetch_add(arr3, 1,
                             __ATOMIC_ACQ_REL, __HIP_MEMORY_SCOPE_AGENT);
        if (prev == 2 * B - 1) {
            for (int bb = 0; bb < B; ++bb)
                out[bb] = __hip_atomic_load(&wloss[bb],
                              __ATOMIC_RELAXED, __HIP_MEMORY_SCOPE_AGENT);
        }
    }
}

extern "C" void kernel_launch(void* const* d_in, const int* in_sizes, int n_in,
                              void* d_out, int out_size, void* d_ws, size_t ws_size,
                              hipStream_t stream)
{
    const float* gts   = (const float*)d_in[0];
    const float* preds = (const float*)d_in[1];

    const int N = NPTS;
    const int B = in_sizes[0] / (N * 3);                 // = 4

    const size_t nTot = (size_t)2 * B * N;
    char* p = (char*)d_ws;
    unsigned long long* keys = (unsigned long long*)p;   p += nTot * sizeof(unsigned long long);
    int*   cnt   = (int*)p;                              p += nTot * sizeof(int);
    int*   arr1  = (int*)p;                              p += (size_t)2 * B * QCH * sizeof(int);
    int*   arr2  = (int*)p;                              p += (size_t)2 * B * sizeof(int);
    int*   arr3  = (int*)p;                              p += sizeof(int);
    float* wloss = (float*)p;                            p += (size_t)B * sizeof(float);

    const size_t zeroBytes = (size_t)(p - (char*)cnt);
    hipMemsetAsync(keys, 0xFF, nTot * sizeof(unsigned long long), stream);
    hipMemsetAsync(cnt, 0, zeroBytes, stream);

    dim3 gA(QCH, NSLICE, B * 2);                         // 8 x 16 x 8 = 1024 blocks
    dacl_fused<<<gA, BLK, 0, stream>>>(gts, preds, keys, cnt, arr1, arr2, arr3,
                                       wloss, (float*)d_out, B, N);
}

// Round 5
// 136.995 us; speedup vs baseline: 1.7035x; 1.7035x over previous
//
#include <hip/hip_runtime.h>
#include <math.h>

// Density-Aware Chamfer Loss, B=4, N=8192, fp32 3D points.
// NN argmin in expanded form k_j = |t_j|^2 - 2 q.t_j (same argmin as true dist).
// Target slices staged in LDS; per-slice partial argmins merged via packed u64
// atomicMin: key = (monotone_f32(k) << 32) | idx -> lowest-index tie-break,
// matching jnp.argmin. Loss recomputes the true distance from idx (exact).
//
// Round-5 config: QPT=8 (halves LDS-pipe load vs QPT=4: one broadcast
// ds_read_b128 feeds 512 pairs) AND 1024 blocks (4/CU, 4 waves/SIMD) for
// latency cover — round 3 had the former, round 2 the latter; this has both.
// Hot loop is plain tile[j] + unroll 4: the compiler batches 4 independent
// ds_reads ahead (round-4's manual rotation serialized them — regression).
//
// ws layout: [keys: 2*B*N u64 (512KB)][cnt: 2*B*N int (256KB)]
// Dispatches: memset(keys=0xFF) -> partial(+zero cnt) -> count(+zero out) -> loss.

#define NPTS   8192
#define QPT    8                    // queries per thread
#define BLK    256
#define TSL    256                  // targets per slice (4KB LDS as float4)
#define NSLICE (NPTS / TSL)         // 32
#define QCH    (NPTS / (QPT * BLK)) // 4

__global__ __launch_bounds__(BLK) void dacl_partial(
    const float* __restrict__ gts, const float* __restrict__ preds,
    unsigned long long* __restrict__ keys, int* __restrict__ cnt, int B, int N)
{
    const int bz  = blockIdx.z;      // dir*B + b
    const int dir = bz / B;
    const int b   = bz - dir * B;

    // fold cnt zeroing into this kernel (cnt is first read by dacl_count,
    // which launches after us -> kernel boundary orders it)
    if (blockIdx.y == 0) {
        const int nblk  = QCH * 2 * B;            // 32 blocks share the job
        const int blk   = blockIdx.x + QCH * bz;
        const int total = 2 * B * N;              // ints
        const int per   = total / nblk;           // 2048
        int* p = cnt + blk * per;
        for (int k = threadIdx.x; k < per; k += BLK) p[k] = 0;
    }

    const float* __restrict__ q = (dir == 0 ? gts : preds) + (size_t)b * N * 3;
    const float* __restrict__ t = (dir == 0 ? preds : gts) + (size_t)b * N * 3;

    __shared__ float4 tile[TSL];
    const int tbase = blockIdx.y * TSL;

    // stage target slice: (tx,ty,tz,|t|^2) per point
    if (threadIdx.x < TSL) {
        const int j = tbase + threadIdx.x;
        const float tx = t[3 * j], ty = t[3 * j + 1], tz = t[3 * j + 2];
        tile[threadIdx.x] = make_float4(tx, ty, tz, tx * tx + ty * ty + tz * tz);
    }
    __syncthreads();

    float m2x[QPT], m2y[QPT], m2z[QPT], best[QPT];
    int   bi[QPT];
    const int qbase = blockIdx.x * (QPT * BLK);
    #pragma unroll
    for (int u = 0; u < QPT; ++u) {
        const int i = qbase + u * BLK + threadIdx.x;   // coalesced across lanes
        m2x[u]  = -2.0f * q[3 * i];
        m2y[u]  = -2.0f * q[3 * i + 1];
        m2z[u]  = -2.0f * q[3 * i + 2];
        best[u] = 3.402823466e38f;
        bi[u]   = 0;
    }

    // hot loop: 1 broadcast ds_read_b128 + QPT*(3 fma + cmp + 2 sel);
    // unroll 4 lets the compiler keep 4 ds_reads in flight
    #pragma unroll 4
    for (int j = 0; j < TSL; ++j) {
        const float4 tv = tile[j];
        #pragma unroll
        for (int u = 0; u < QPT; ++u) {
            const float k = fmaf(m2x[u], tv.x,
                            fmaf(m2y[u], tv.y,
                            fmaf(m2z[u], tv.z, tv.w)));
            if (k < best[u]) { best[u] = k; bi[u] = j; }  // strict <: first-min in-slice
        }
    }

    const size_t obase = (size_t)bz * N;
    #pragma unroll
    for (int u = 0; u < QPT; ++u) {
        const int i = qbase + u * BLK + threadIdx.x;
        unsigned int ub = __float_as_uint(best[u]);
        ub = ((int)ub < 0) ? ~ub : (ub | 0x80000000u);   // monotone f32->u32 (k can be <0)
        const unsigned long long key =
            ((unsigned long long)ub << 32) | (unsigned int)(tbase + bi[u]);
        atomicMin(&keys[obase + i], key);                // equal dist -> smallest idx wins
    }
}

__global__ __launch_bounds__(256) void dacl_count(
    const unsigned long long* __restrict__ keys, int* __restrict__ cnt,
    float* __restrict__ out, int out_size, int total, int N)
{
    const int i = blockIdx.x * 256 + threadIdx.x;
    if (blockIdx.x == 0 && threadIdx.x < out_size) out[threadIdx.x] = 0.0f;
    if (i >= total) return;
    const int idx = (int)(keys[i] & 0xFFFFFFFFull);
    const int seg = i / N;                               // dir*B + b
    atomicAdd(&cnt[seg * N + idx], 1);
}

__global__ __launch_bounds__(256) void dacl_loss(
    const float* __restrict__ gts, const float* __restrict__ preds,
    const unsigned long long* __restrict__ keys, const int* __restrict__ cnt,
    float* __restrict__ out, int B, int N)
{
    const int bz  = blockIdx.y;      // dir*B + b
    const int dir = bz / B;
    const int b   = bz - dir * B;
    const float* __restrict__ q = (dir == 0 ? gts : preds) + (size_t)b * N * 3;
    const float* __restrict__ t = (dir == 0 ? preds : gts) + (size_t)b * N * 3;
    const size_t base = (size_t)bz * N;

    float s = 0.0f;
    for (int i = blockIdx.x * 256 + threadIdx.x; i < N; i += 32 * 256) {
        const int idx = (int)(keys[base + i] & 0xFFFFFFFFull);
        // recompute true NN distance exactly like the reference's gather form
        const float dx = q[3 * i]     - t[3 * idx];
        const float dy = q[3 * i + 1] - t[3 * idx + 1];
        const float dz = q[3 * i + 2] - t[3 * idx + 2];
        const float d  = dx * dx + dy * dy + dz * dz;
        const float c  = (float)cnt[base + idx];         // count^N_LAMBDA, N_LAMBDA=1
        s += 1.0f - expf(-d) / (c + 1e-6f);              // frac terms are 1 (n_x == n_gt)
    }
    for (int off = 32; off > 0; off >>= 1) s += __shfl_down(s, off, 64);
    if ((threadIdx.x & 63) == 0)
        atomicAdd(&out[b], s / (2.0f * (float)N));       // (mean1+mean2)/2
}

extern "C" void kernel_launch(void* const* d_in, const int* in_sizes, int n_in,
                              void* d_out, int out_size, void* d_ws, size_t ws_size,
                              hipStream_t stream)
{
    const float* gts   = (const float*)d_in[0];
    const float* preds = (const float*)d_in[1];

    const int N = NPTS;
    const int B = in_sizes[0] / (N * 3);                 // = 4

    const size_t nTot = (size_t)2 * B * N;
    unsigned long long* keys = (unsigned long long*)d_ws;
    int* cnt = (int*)((char*)d_ws + nTot * sizeof(unsigned long long));

    hipMemsetAsync(keys, 0xFF, nTot * sizeof(unsigned long long), stream);

    dim3 gA(QCH, NSLICE, B * 2);                         // 4 x 32 x 8 = 1024 blocks
    dacl_partial<<<gA, BLK, 0, stream>>>(gts, preds, keys, cnt, B, N);

    dacl_count<<<(int)((nTot + 255) / 256), 256, 0, stream>>>(
        keys, cnt, (float*)d_out, out_size, (int)nTot, N);

    dim3 gC(32, B * 2);
    dacl_loss<<<gC, 256, 0, stream>>>(gts, preds, keys, cnt, (float*)d_out, B, N);
}